// Round 3
// baseline (201.678 us; speedup 1.0000x reference)
//
#include <hip/hip_runtime.h>
#include <hip/hip_bf16.h>

// Head attention: B=16, T=2048, C=512(n_embd), H=64(head)
// out[b,t,h] = softmax_causal( (x@Wq)(x@Wk)^T * C^-0.5 ) @ (x@Wv)

#define B_ 16
#define T_ 2048
#define C_ 512
#define LOG2E 1.4426950408889634f

typedef __attribute__((ext_vector_type(4))) float f32x4;
typedef __attribute__((ext_vector_type(8))) short bf16x8;

__device__ inline unsigned short f2bf(float f) {
    unsigned int u = __builtin_bit_cast(unsigned int, f);
    u += 0x7fff + ((u >> 16) & 1);   // RNE
    return (unsigned short)(u >> 16);
}

__device__ inline f32x4 mfma16(bf16x8 a, bf16x8 b, f32x4 c) {
    return __builtin_amdgcn_mfma_f32_16x16x32_bf16(a, b, c, 0, 0, 0);
}

// ---------------------------------------------------------------------------
// prep: Wt[n][k] = W[k][n] bf16 (n: 0-63 K, 64-127 Q (x scale), 128-191 V).
// Coalesced READS (writes scatter, absorbed by store buffering).
// ---------------------------------------------------------------------------
__global__ void prep_kernel(const float* __restrict__ Wk, const float* __restrict__ Wq,
                            const float* __restrict__ Wv, unsigned short* __restrict__ Wt,
                            int* __restrict__ fe) {
    if (blockIdx.x == 384) {
        if (threadIdx.x < B_) fe[threadIdx.x] = T_;
        return;
    }
    int id = blockIdx.x * 256 + threadIdx.x;     // [0, 3*32768)
    int mtx = id >> 15, rem = id & 32767;
    int k = rem >> 6, nl = rem & 63;
    const float* W = (mtx == 0) ? Wk : ((mtx == 1) ? Wq : Wv);
    float v = W[rem];                            // coalesced
    if (mtx == 1) v *= 0.04419417382415922f;     // 1/sqrt(512) folded into Q
    Wt[(mtx * 64 + nl) * 512 + k] = f2bf(v);
}

__global__ void scan_kernel(const int* __restrict__ idx, int* __restrict__ fe) {
    int i = blockIdx.x * 256 + threadIdx.x;
    if (idx[i] == 32000) atomicMin(&fe[i >> 11], i & 2047);
}

// ---------------------------------------------------------------------------
// qkv: 64 tokens/block. Whole x-tile (64x512) staged to LDS ONCE (coalesced,
// one barrier), then barrier-free compute: wave w owns features 16w..16w+15 of
// K, Q and V; W-fragments read directly from L2-hot Wt. V computed transposed
// (swap MFMA operands). Coalesced stores via LDS epilogue.
// ---------------------------------------------------------------------------
__global__ __launch_bounds__(256) void qkv_kernel(
        const float* __restrict__ x, const unsigned short* __restrict__ Wt,
        unsigned short* __restrict__ Qm, unsigned short* __restrict__ Km,
        unsigned short* __restrict__ Vt) {
    __shared__ __align__(16) unsigned short xs[64 * 512];   // 64 KB
    int tid = threadIdx.x, wave = tid >> 6, lane = tid & 63;
    int m16 = lane & 15, quad = lane >> 4;
    int row0 = blockIdx.x * 64;

    // phase 1: x tile -> LDS bf16, swizzled (group g ^= row&7)
#pragma unroll
    for (int i = 0; i < 16; i++) {
        int u = tid + i * 256;                   // 4096 units of 8 floats
        int row = u >> 6, cu = u & 63;
        const f32x4* p = (const f32x4*)(x + (long)(row0 + row) * C_ + cu * 8);
        f32x4 a = p[0], bq = p[1];
        bf16x8 t;
#pragma unroll
        for (int j = 0; j < 4; j++) { t[j] = (short)f2bf(a[j]); t[4 + j] = (short)f2bf(bq[j]); }
        *(bf16x8*)&xs[row * 512 + ((cu ^ (row & 7)) * 8)] = t;
    }
    __syncthreads();

    f32x4 ka[4], qa[4], va[4];
#pragma unroll
    for (int i = 0; i < 4; i++) {
        ka[i] = (f32x4){0.f, 0.f, 0.f, 0.f};
        qa[i] = (f32x4){0.f, 0.f, 0.f, 0.f};
        va[i] = (f32x4){0.f, 0.f, 0.f, 0.f};
    }
    int krw = (wave * 16 + m16) * 512;           // Wt row bases
    int qrw = (64 + wave * 16 + m16) * 512;
    int vrw = (128 + wave * 16 + m16) * 512;

#pragma unroll 2
    for (int cb = 0; cb < 8; cb++) {
#pragma unroll
        for (int half = 0; half < 2; half++) {
            int kk = cb * 64 + half * 32 + quad * 8;
            bf16x8 wk = *(const bf16x8*)&Wt[krw + kk];
            bf16x8 wq = *(const bf16x8*)&Wt[qrw + kk];
            bf16x8 wv = *(const bf16x8*)&Wt[vrw + kk];
            int g = kk >> 3;
            bf16x8 xf[4];
#pragma unroll
            for (int mt = 0; mt < 4; mt++) {
                int row = mt * 16 + m16;
                xf[mt] = *(const bf16x8*)&xs[row * 512 + ((g ^ (row & 7)) * 8)];
            }
#pragma unroll
            for (int mt = 0; mt < 4; mt++) ka[mt] = mfma16(xf[mt], wk, ka[mt]);
#pragma unroll
            for (int mt = 0; mt < 4; mt++) qa[mt] = mfma16(xf[mt], wq, qa[mt]);
#pragma unroll
            for (int mt = 0; mt < 4; mt++) va[mt] = mfma16(wv, xf[mt], va[mt]);  // V^T
        }
    }
    __syncthreads();                             // all waves done reading xs

    unsigned short* co  = xs;                    // [64][136] K|Q
    unsigned short* vco = xs + 64 * 136;         // [4][16][72] V^T
#pragma unroll
    for (int mt = 0; mt < 4; mt++) {
#pragma unroll
        for (int r = 0; r < 4; r++) {
            int trow = mt * 16 + quad * 4 + r;
            co[trow * 136 + wave * 16 + m16]      = f2bf(ka[mt][r]);
            co[trow * 136 + 64 + wave * 16 + m16] = f2bf(qa[mt][r]);
            vco[wave * 1152 + (quad * 4 + r) * 72 + mt * 16 + m16] = f2bf(va[mt][r]);
        }
    }
    __syncthreads();
#pragma unroll
    for (int i = 0; i < 4; i++) {                // K/Q coalesced b128 stores
        int u = tid + i * 256; int tok = u >> 4; int fg = u & 15;
        bf16x8 vv = *(const bf16x8*)&co[tok * 136 + fg * 8];
        unsigned short* dst = (fg < 8) ? Km : Qm;
        *(bf16x8*)&dst[(long)(row0 + tok) * 64 + (fg & 7) * 8] = vv;
    }
    int bb = row0 >> 11, tl = row0 & 2047;
#pragma unroll
    for (int i = 0; i < 2; i++) {                // V^T coalesced b128 stores
        int u = lane + i * 64; int hl = u >> 3; int tg = u & 7;
        bf16x8 vv = *(const bf16x8*)&vco[wave * 1152 + hl * 72 + tg * 8];
        *(bf16x8*)&Vt[((long)bb * 64 + wave * 16 + hl) * T_ + tl + tg * 8] = vv;
    }
}

// ---------------------------------------------------------------------------
// attn: wave-autonomous flash attention. Each wave owns 16 q-rows, loops over
// 64-key tiles reading K/V fragments DIRECTLY from global (L2-hot; XCD=b%8 so
// each XCD caches only 2 batches' K+V). No __syncthreads in the loop; only a
// wave-private P transpose through LDS. K prefetched one tile ahead. Masked
// diagonal tile is the last iteration only. Softmax denom via ones-column MFMA.
// ---------------------------------------------------------------------------
__global__ __launch_bounds__(256, 2) void attn_kernel(
        const unsigned short* __restrict__ Qm, const unsigned short* __restrict__ Km,
        const unsigned short* __restrict__ Vt, const int* __restrict__ fe,
        float* __restrict__ out) {
    __shared__ __align__(16) unsigned short Plds[4][16 * 64];

    int b = blockIdx.x;                          // XCD = (b + 16*y) % 8 = b % 8
    int tid = threadIdx.x, wave = tid >> 6, lane = tid & 63;
    int m16 = lane & 15, quad = lane >> 4;
    int qt16 = (31 - (int)blockIdx.y) * 4 + wave;  // [0,128), longest first
    int qrow0 = qt16 << 4;
    long bT = (long)b * T_;

    const unsigned short* qp = Qm + (bT + qrow0 + m16) * 64;
    bf16x8 qf0 = *(const bf16x8*)(qp + quad * 8);
    bf16x8 qf1 = *(const bf16x8*)(qp + 32 + quad * 8);

    const unsigned short* Kbase = Km + bT * 64;
    const unsigned short* Vbase = Vt + (long)b * 64 * T_;

    f32x4 o[5];
#pragma unroll
    for (int h = 0; h < 5; h++) o[h] = (f32x4){0.f, 0.f, 0.f, 0.f};
    float mi[4];
#pragma unroll
    for (int r = 0; r < 4; r++) mi[r] = -INFINITY;
    int qloc = qrow0 + quad * 4;

    bf16x8 onesb;                                // B-frag: col 0 = 1.0bf
    {
        short ov = (m16 == 0) ? (short)0x3F80 : (short)0;
#pragma unroll
        for (int j = 0; j < 8; j++) onesb[j] = ov;
    }

    int nfull = qt16 >> 2;                       // full tiles; tile nfull = diag
    bf16x8 kf[8];
#pragma unroll
    for (int ns = 0; ns < 4; ns++)
#pragma unroll
        for (int h = 0; h < 2; h++)
            kf[ns * 2 + h] = *(const bf16x8*)&Kbase[(ns * 16 + m16) * 64 + h * 32 + quad * 8];

    unsigned short* pw = Plds[wave];

    for (int kt = 0; kt <= nfull; kt++) {
        bf16x8 vf[8];                            // V frags, consumed post-softmax
#pragma unroll
        for (int hs = 0; hs < 4; hs++)
#pragma unroll
            for (int h = 0; h < 2; h++)
                vf[hs * 2 + h] = *(const bf16x8*)&Vbase[(hs * 16 + m16) * T_ + kt * 64 + h * 32 + quad * 8];

        f32x4 s[4];
#pragma unroll
        for (int ns = 0; ns < 4; ns++) {
            f32x4 z = (f32x4){0.f, 0.f, 0.f, 0.f};
            z = mfma16(qf0, kf[ns * 2], z);
            z = mfma16(qf1, kf[ns * 2 + 1], z);
            s[ns] = z;
        }

        if (kt < nfull) {                        // prefetch next K tile
#pragma unroll
            for (int ns = 0; ns < 4; ns++)
#pragma unroll
                for (int h = 0; h < 2; h++)
                    kf[ns * 2 + h] = *(const bf16x8*)
                        &Kbase[((kt + 1) * 64 + ns * 16 + m16) * 64 + h * 32 + quad * 8];
        } else {                                 // diagonal tile: causal mask
#pragma unroll
            for (int ns = 0; ns < 4; ns++) {
                int n = kt * 64 + ns * 16 + m16;
#pragma unroll
                for (int r = 0; r < 4; r++)
                    if (n > qloc + r) s[ns][r] = -INFINITY;
            }
        }

#pragma unroll
        for (int r = 0; r < 4; r++) {
            float mx = fmaxf(fmaxf(s[0][r], s[1][r]), fmaxf(s[2][r], s[3][r]));
            mx = fmaxf(mx, mi[r]);
#pragma unroll
            for (int off = 1; off < 16; off <<= 1)
                mx = fmaxf(mx, __shfl_xor(mx, off));
            float alpha = exp2f((mi[r] - mx) * LOG2E);
            mi[r] = mx;
#pragma unroll
            for (int ns = 0; ns < 4; ns++)
                s[ns][r] = exp2f((s[ns][r] - mx) * LOG2E);
#pragma unroll
            for (int h = 0; h < 5; h++) o[h][r] *= alpha;
        }

        // P: C-layout -> A-layout via wave-private LDS (in-order DS pipe)
#pragma unroll
        for (int ns = 0; ns < 4; ns++)
#pragma unroll
            for (int r = 0; r < 4; r++) {
                int mrow = quad * 4 + r;
                pw[mrow * 64 + ((ns * 16 + m16) ^ ((mrow & 7) * 8))] = f2bf(s[ns][r]);
            }
        int aswz = (m16 & 7) * 8;
        bf16x8 pa0 = *(const bf16x8*)&pw[m16 * 64 + ((quad * 8) ^ aswz)];
        bf16x8 pa1 = *(const bf16x8*)&pw[m16 * 64 + ((32 + quad * 8) ^ aswz)];

#pragma unroll
        for (int hs = 0; hs < 4; hs++) {
            o[hs] = mfma16(pa0, vf[hs * 2], o[hs]);
            o[hs] = mfma16(pa1, vf[hs * 2 + 1], o[hs]);
        }
        o[4] = mfma16(pa0, onesb, o[4]);         // denominator
        o[4] = mfma16(pa1, onesb, o[4]);
    }

    int feb = fe[b];
#pragma unroll
    for (int r = 0; r < 4; r++) {
        int t = qloc + r;
        float l = __shfl(o[4][r], lane & 48);    // broadcast from m16==0 lane
        float inv = 1.0f / l;
        bool dead = (t >= feb);
#pragma unroll
        for (int hs = 0; hs < 4; hs++) {
            float val = dead ? __builtin_nanf("") : o[hs][r] * inv;
            out[(bT + t) * 64 + hs * 16 + m16] = val;
        }
    }
}

// ---------------------------------------------------------------------------
extern "C" void kernel_launch(void* const* d_in, const int* in_sizes, int n_in,
                              void* d_out, int out_size, void* d_ws, size_t ws_size,
                              hipStream_t stream) {
    const float* x  = (const float*)d_in[0];
    const float* Wk = (const float*)d_in[1];
    const float* Wq = (const float*)d_in[2];
    const float* Wv = (const float*)d_in[3];
    const int* idx  = (const int*)d_in[4];
    float* out = (float*)d_out;

    char* ws = (char*)d_ws;
    int* fe            = (int*)ws;                                 //    64 B
    unsigned short* Wt = (unsigned short*)(ws + 1024);             //  192 KiB
    unsigned short* Qm = (unsigned short*)(ws + 262144);           //    4 MiB
    unsigned short* Km = (unsigned short*)(ws + 262144 + 4194304); //    4 MiB
    unsigned short* Vt = (unsigned short*)(ws + 262144 + 8388608); //    4 MiB

    prep_kernel<<<385, 256, 0, stream>>>(Wk, Wq, Wv, Wt, fe);
    scan_kernel<<<128, 256, 0, stream>>>(idx, fe);
    qkv_kernel<<<512, 256, 0, stream>>>(x, Wt, Qm, Km, Vt);
    dim3 ga(16, 32);
    attn_kernel<<<ga, 256, 0, stream>>>(Qm, Km, Vt, fe, out);
}